// Round 2
// baseline (2098.167 us; speedup 1.0000x reference)
//
#include <hip/hip_runtime.h>

#define T_STEPS 4096
#define OBS 128
#define D_LOG2PI 1.8378770664093453

// ws layout (bytes)
#define OFF_Y    0           // double[4096][2] : group sums of y
#define OFF_C1   65536       // float4[4096][2] : {ub,vb,PsiI,CG},{gam,Gq,invd,c}
#define OFF_P3   196608      // float4[4096][2] : per-group {xp, o2, c, invd}
#define OFF_LD   327680      // double : logdet + const correction (from K1)
#define OFF_CORR 327688      // double : data-dependent ll correction (from K2)

// ---------------------------------------------------------------------------
// K0: per-step per-group sums of observations. 2 steps per 256-thread block,
// one wave per (step, group); pure shuffle reduction, coalesced loads.
// ---------------------------------------------------------------------------
__global__ void __launch_bounds__(256) k_ysum(const float* __restrict__ obs,
                                              double* __restrict__ Y) {
    int tid = threadIdx.x;
    int wave = tid >> 6, lane = tid & 63;
    int step = blockIdx.x * 2 + (wave >> 1);
    int grp = wave & 1;
    double v = (double)obs[step * OBS + grp * 64 + lane];
#pragma unroll
    for (int off = 32; off; off >>= 1) v += __shfl_down(v, off);
    if (lane == 0) Y[step * 2 + grp] = v;
}

// ---------------------------------------------------------------------------
// K1: collapsed covariance (Riccati) recursion. Group-swap + within-group
// permutation symmetry collapse the 132x132 recursion to 6 scalars:
// X00(=X11), X02(=X13), X22(=X33), va=Cov(a,b_r), vc=Cov(c,b_r), fb=J-coeff
// of bias cov. Deviation-channel variance eps_t = s2*b/(s2+t*b) is closed
// form; S = delta*I + sigma*J inverts by Woodbury. Per-step constants
// (c, invd, tau) computed incrementally off the critical chain. logdet's
// 128*log(delta) part telescopes analytically; only sum(log tsig) is
// accumulated. Emits per-step gain coeffs for K2/K3 and final post_cov.
// ---------------------------------------------------------------------------
__global__ void k_phase1(const float* __restrict__ lbs,
                         const float* __restrict__ lon,
                         const float* __restrict__ ltn,
                         float4* __restrict__ C1,
                         double* __restrict__ LD,
                         float* __restrict__ out) {
    if (threadIdx.x != 0) return;
    double beta = exp(2.0 * (double)lbs[0]);       // bias_scale^2
    double s2   = exp(2.0 * (double)lon[0]);       // obs_noise^2
    double q2   = exp(2.0 * (double)ltn[0]);       // trans_noise^2
    const double q2_3 = q2 * (1.0 / 3.0), q2_2 = 0.5 * q2;
    const double inv_s2 = 1.0 / s2;
    double den = s2;                               // s2 + t*beta
    double X00 = 100.0, X02 = 0.0, X22 = 100.0;
    double va = 0.0, vc = 0.0, fb = 0.0;
    double ltacc = 0.0;
    for (int t = 0; t < T_STEPS; ++t) {
        // per-step closed-form constants (independent of recursion state)
        double den1 = den + beta;
        double r1 = 1.0 / den1;
        double c = beta * r1;                      // = eps/delta
        double invd = den * r1 * inv_s2;           // = 1/delta
        double tau = 64.0 * invd;
        den = den1;
        // predict
        double Xp00 = X00 + 2.0 * X02 + X22 + q2_3;
        double Xp02 = X02 + X22 + q2_2;
        double Xp22 = X22 + q2;
        double pa = va + vc;
        // innovation core: S = delta*I + sigma*J, sigma = nsig
        double nsig = Xp00 + 2.0 * pa + fb;
        double tsig = 1.0 + tau * nsig;            // (delta+64sig)/delta
        double Psi = (double)(1.0f / (float)tsig);
        Psi = Psi * (2.0 - tsig * Psi);            // 1 f64 NR -> ~1e-14
        double G = nsig * Psi;
        double phi = tau * Psi;                    // 1'S^-1 1
        double ub = Xp00 + pa;                     // Cov(a_p, y_r)
        double vb = Xp02 + vc;                     // Cov(c_p, y_r)
        double gam = pa + fb;                      // common part of Cov(b_j,y_r)
        double k = phi * gam + c * Psi;
        // covariance update
        X00 = Xp00 - phi * ub * ub;
        X02 = Xp02 - phi * ub * vb;
        X22 = Xp22 - phi * vb * vb;
        va = pa - k * ub;
        vc = vc - k * vb;
        double w = gam * (k + c * Psi) - c * c * G;
        fb = fb - w;
        ltacc += (double)__logf((float)tsig);
        C1[t * 2 + 0] = make_float4((float)ub, (float)vb,
                                    (float)(Psi * invd), (float)(c * G * invd));
        C1[t * 2 + 1] = make_float4((float)gam, (float)(G * invd * invd),
                                    (float)invd, (float)c);
    }
    // telescoped: sum_t log(delta_t) = 4095*log(s2) + log(s2 + 4096*beta)
    double sld = (T_STEPS - 1) * log(s2) + log(den);   // den == s2+4096*beta
    LD[0] = -0.5 * (128.0 * sld + 2.0 * ltacc) - T_STEPS * 64.0 * D_LOG2PI;
    // post_cov (4x4 row-major); cross-group zeros are exact
    out[5 + 0]  = (float)X00; out[5 + 1]  = 0.0f;      out[5 + 2]  = (float)X02; out[5 + 3]  = 0.0f;
    out[5 + 4]  = 0.0f;       out[5 + 5]  = (float)X00; out[5 + 6]  = 0.0f;      out[5 + 7]  = (float)X02;
    out[5 + 8]  = (float)X02; out[5 + 9]  = 0.0f;      out[5 + 10] = (float)X22; out[5 + 11] = 0.0f;
    out[5 + 12] = 0.0f;       out[5 + 13] = (float)X02; out[5 + 14] = 0.0f;      out[5 + 15] = (float)X22;
}

// ---------------------------------------------------------------------------
// K2: 6-dim mean recursion (two independent per-group (pos, vel, bias-sum)
// channels), driven by group sums Y_g. Accumulates the data-dependent ll
// correction 0.5 * G/delta^2 * R_g^2 per step per group.
// ---------------------------------------------------------------------------
__global__ void k_phase2(const float4* __restrict__ C1,
                         const double* __restrict__ Y,
                         const double* __restrict__ LD,
                         float4* __restrict__ P3,
                         double* __restrict__ corr_out,
                         float* __restrict__ out) {
    if (threadIdx.x != 0) return;
    double xA0 = 0, xV0 = 0, B0 = 0, xA1 = 0, xV1 = 0, B1 = 0, corr = 0;
    for (int t = 0; t < T_STEPS; ++t) {
        float4 c1a = C1[t * 2], c1b = C1[t * 2 + 1];
        double ub = (double)c1a.x, vb = (double)c1a.y;
        double PsiI = (double)c1a.z, CG = (double)c1a.w;
        double gam = (double)c1b.x, Gq = (double)c1b.y;
        double invd = (double)c1b.z, c = (double)c1b.w;
        double Y0 = Y[t * 2], Y1 = Y[t * 2 + 1];
        double xp0 = xA0 + xV0, xp1 = xA1 + xV1;
        double R0 = Y0 - 64.0 * xp0 - B0;          // group-sum residual
        double R1 = Y1 - 64.0 * xp1 - B1;
        double s0 = PsiI * R0, s1 = PsiI * R1;
        xA0 = xp0 + ub * s0; xV0 = xV0 + vb * s0;
        xA1 = xp1 + ub * s1; xV1 = xV1 + vb * s1;
        double o20 = gam * s0 - CG * R0;           // group-common bias incr
        double o21 = gam * s1 - CG * R1;
        B0 = B0 + c * R0 + 64.0 * o20;
        B1 = B1 + c * R1 + 64.0 * o21;
        corr += 0.5 * Gq * (R0 * R0 + R1 * R1);
        P3[t * 2 + 0] = make_float4((float)xp0, (float)o20, (float)c, (float)invd);
        P3[t * 2 + 1] = make_float4((float)xp1, (float)o21, (float)c, (float)invd);
    }
    corr_out[0] = corr + LD[0];
    out[1] = (float)xA0; out[2] = (float)xA1; out[3] = (float)xV0; out[4] = (float)xV1;
}

// ---------------------------------------------------------------------------
// K3: 128 independent per-sensor bias recursions b' = b + c*r + o2,
// accumulating Sq = sum_t r^2/delta. LDS double-buffered chunks.
// logp = -0.5*Sq_total + corr.
// ---------------------------------------------------------------------------
#define CH 32
__global__ void __launch_bounds__(128) k_phase3(const float* __restrict__ obs,
                                                const float4* __restrict__ P3,
                                                const double* __restrict__ corr_in,
                                                float* __restrict__ out) {
    __shared__ float ybuf[2][CH][OBS];
    __shared__ float4 cbuf[2][CH][2];
    __shared__ double part[2];
    int tid = threadIdx.x;
    int g = tid >> 6;
    float yr[CH];
    float4 cr;
    // prologue: stage chunk 0
#pragma unroll
    for (int r = 0; r < CH; ++r) yr[r] = obs[r * OBS + tid];
    if (tid < 2 * CH) cr = P3[tid];
#pragma unroll
    for (int r = 0; r < CH; ++r) ybuf[0][r][tid] = yr[r];
    if (tid < 2 * CH) cbuf[0][tid >> 1][tid & 1] = cr;
    __syncthreads();

    double b = 0.0, acc = 0.0;
    for (int kch = 0; kch < T_STEPS / CH; ++kch) {
        int cur = kch & 1, nxt = cur ^ 1;
        bool more = (kch + 1 < T_STEPS / CH);
        int t0n = (kch + 1) * CH;
        if (more) {
#pragma unroll
            for (int r = 0; r < CH; ++r) yr[r] = obs[(t0n + r) * OBS + tid];
            if (tid < 2 * CH) cr = P3[t0n * 2 + tid];
        }
#pragma unroll
        for (int r = 0; r < CH; ++r) {
            float4 cf = cbuf[cur][r][g];
            double y = (double)ybuf[cur][r][tid];
            double xp = (double)cf.x, o2 = (double)cf.y;
            double c = (double)cf.z, invd = (double)cf.w;
            double rr = (y - xp) - b;
            acc = fma(rr * rr, invd, acc);
            b = fma(c, rr, b + o2);
        }
        __syncthreads();
        if (more) {
#pragma unroll
            for (int r = 0; r < CH; ++r) ybuf[nxt][r][tid] = yr[r];
            if (tid < 2 * CH) cbuf[nxt][tid >> 1][tid & 1] = cr;
        }
        __syncthreads();
    }
#pragma unroll
    for (int off = 32; off; off >>= 1) acc += __shfl_down(acc, off);
    if ((tid & 63) == 0) part[tid >> 6] = acc;
    __syncthreads();
    if (tid == 0) out[0] = (float)(-0.5 * (part[0] + part[1]) + corr_in[0]);
}

extern "C" void kernel_launch(void* const* d_in, const int* in_sizes, int n_in,
                              void* d_out, int out_size, void* d_ws, size_t ws_size,
                              hipStream_t stream) {
    const float* obs = (const float*)d_in[0];
    const float* lbs = (const float*)d_in[1];
    const float* lon = (const float*)d_in[2];
    const float* ltn = (const float*)d_in[3];
    float* out = (float*)d_out;
    char* ws = (char*)d_ws;
    double* Y = (double*)(ws + OFF_Y);
    float4* C1 = (float4*)(ws + OFF_C1);
    float4* P3 = (float4*)(ws + OFF_P3);
    double* LD = (double*)(ws + OFF_LD);
    double* corr = (double*)(ws + OFF_CORR);

    k_ysum<<<T_STEPS / 2, 256, 0, stream>>>(obs, Y);
    k_phase1<<<1, 64, 0, stream>>>(lbs, lon, ltn, C1, LD, out);
    k_phase2<<<1, 64, 0, stream>>>(C1, Y, LD, P3, corr, out);
    k_phase3<<<1, 128, 0, stream>>>(obs, P3, corr, out);
}

// Round 3
// 1082.123 us; speedup vs baseline: 1.9389x; 1.9389x over previous
//
#include <hip/hip_runtime.h>

#define T_STEPS 4096
#define OBS 128
#define D_LOG2PI 1.8378770664093453
#define D_LOG64  4.158883083359672

// ws layout (bytes)
#define OFF_YB   0         // double[4096][2] : per-group MEANS of y
#define OFF_DC   65536     // double2[4096]   : {w_t, inv_delta_t} deviation consts
#define OFF_PART 131072    // double          : common-sector partial logp

// ---------------------------------------------------------------------------
// K0: per-step per-group means of observations + closed-form deviation-sector
// constants. w_t = beta/(s2+t*beta) (posterior scale of the prefix sum),
// delta_t = eps_t + s2 with eps_t = s2*beta/(s2+t*beta).
// ---------------------------------------------------------------------------
__global__ void __launch_bounds__(256) k_prep(const float* __restrict__ obs,
                                              const float* __restrict__ lbs,
                                              const float* __restrict__ lon,
                                              double* __restrict__ Yb,
                                              double2* __restrict__ DC) {
    int tid = threadIdx.x;
    int wave = tid >> 6, lane = tid & 63;
    int step = blockIdx.x * 2 + (wave >> 1);
    int grp = wave & 1;
    double v = (double)obs[step * OBS + grp * 64 + lane];
#pragma unroll
    for (int off = 32; off; off >>= 1) v += __shfl_down(v, off);
    if (lane == 0) Yb[step * 2 + grp] = v * (1.0 / 64.0);
    if (grp == 0 && lane == 1) {
        double beta = exp(2.0 * (double)lbs[0]);
        double s2   = exp(2.0 * (double)lon[0]);
        double den  = fma((double)step, beta, s2);          // s2 + t*beta
        // w = beta/den ; inv_delta = den / (s2*(den+beta))
        DC[step] = make_double2(beta / den, den / (s2 * (den + beta)));
    }
}

// ---------------------------------------------------------------------------
// K1: fused common-sector filter. EXACT decoupling: group-mean channel is a
// clean time-invariant 3x3 Kalman filter on (pos, vel, bbar) with measurement
// noise s2/64; BOTH groups share one Riccati (identical parameters), only the
// mean recursions differ. No per-step stores, no f64 divides (f32-seeded
// reciprocal + 2 Newton steps). Accumulates sum R^2/Sc and sum log Sc.
// ---------------------------------------------------------------------------
__global__ void k_common(const float* __restrict__ lbs,
                         const float* __restrict__ lon,
                         const float* __restrict__ ltn,
                         const double* __restrict__ Yb,
                         double* __restrict__ part,
                         float* __restrict__ out) {
    if (threadIdx.x != 0) return;
    const double beta = exp(2.0 * (double)lbs[0]);
    const double s2   = exp(2.0 * (double)lon[0]);
    const double q2   = exp(2.0 * (double)ltn[0]);
    const double q23 = q2 * (1.0 / 3.0), q22 = 0.5 * q2;
    const double rbar = s2 * (1.0 / 64.0);
    double Paa = 100.0, Pac = 0.0, PaB = 0.0;
    double Pcc = 100.0, PcB = 0.0, PBB = beta * (1.0 / 64.0);
    double p0 = 0, v0 = 0, B0 = 0, p1 = 0, v1 = 0, B1 = 0;
    double accR = 0.0, accL = 0.0;
    const double2* Yp = (const double2*)Yb;

#define CSTEP(YY) do { \
    double Xaa = fma(2.0, Pac, Paa) + Pcc + q23; \
    double Xac = Pac + Pcc + q22; \
    double Xcc = Pcc + q2; \
    double XaB = PaB + PcB; \
    double ua = Xaa + XaB; \
    double uc = Xac + PcB; \
    double uB = XaB + PBB; \
    double Sc = ua + uB + rbar; \
    double rc = (double)(1.0f / (float)Sc); \
    rc = fma(fma(-Sc, rc, 1.0), rc, rc); \
    rc = fma(fma(-Sc, rc, 1.0), rc, rc); \
    p0 += v0; p1 += v1; \
    double R0 = YY.x - p0 - B0; \
    double R1 = YY.y - p1 - B1; \
    double s0 = R0 * rc, s1 = R1 * rc; \
    p0 = fma(ua, s0, p0); v0 = fma(uc, s0, v0); B0 = fma(uB, s0, B0); \
    p1 = fma(ua, s1, p1); v1 = fma(uc, s1, v1); B1 = fma(uB, s1, B1); \
    accR = fma(fma(R0, R0, R1 * R1), rc, accR); \
    accL += (double)__logf((float)Sc); \
    double ta = ua * rc, tc = uc * rc, tB = uB * rc; \
    Paa = fma(-ta, ua, Xaa); Pac = fma(-ta, uc, Xac); PaB = fma(-ta, uB, XaB); \
    Pcc = fma(-tc, uc, Xcc); PcB = fma(-tc, uB, PcB); \
    PBB = fma(-tB, uB, PBB); \
} while (0)

    double2 bufA[8], bufB[8];
#pragma unroll
    for (int r = 0; r < 8; ++r) bufA[r] = Yp[r];
    for (int ch = 0; ch < 512; ch += 2) {
        int nb = (ch + 1) * 8;
#pragma unroll
        for (int r = 0; r < 8; ++r) bufB[r] = Yp[nb + r];
#pragma unroll
        for (int r = 0; r < 8; ++r) CSTEP(bufA[r]);
        int na = (ch + 2 < 512 ? ch + 2 : 511) * 8;
#pragma unroll
        for (int r = 0; r < 8; ++r) bufA[r] = Yp[na + r];
#pragma unroll
        for (int r = 0; r < 8; ++r) CSTEP(bufB[r]);
    }
#undef CSTEP

    // telescoped deviation logdet: sum_t log(delta_t) = (T-1)log(s2)+log(s2+T*beta)
    double sld = (double)(T_STEPS - 1) * log(s2) + log(fma((double)T_STEPS, beta, s2));
    part[0] = -0.5 * accR - accL - 63.0 * sld
              - (double)T_STEPS * (D_LOG64 + 64.0 * D_LOG2PI);
    out[1] = (float)p0; out[2] = (float)p1; out[3] = (float)v0; out[4] = (float)v1;
    out[5]  = (float)Paa; out[6]  = 0.0f;       out[7]  = (float)Pac; out[8]  = 0.0f;
    out[9]  = 0.0f;       out[10] = (float)Paa; out[11] = 0.0f;       out[12] = (float)Pac;
    out[13] = (float)Pac; out[14] = 0.0f;       out[15] = (float)Pcc; out[16] = 0.0f;
    out[17] = 0.0f;       out[18] = (float)Pac; out[19] = 0.0f;       out[20] = (float)Pcc;
}

// ---------------------------------------------------------------------------
// K2: deviation sector in CLOSED FORM. Posterior deviation mean is a scaled
// prefix sum: dhat_t,j = w_t * E_t,j, E_t,j = sum_{tau<t} (y_tau,j - ybar_tau).
// Thread j owns sensor j; critical chain is 1 f64 add/step. Accumulates
// Sq = sum rho^2/delta and combines with the common-sector partial.
// ---------------------------------------------------------------------------
__global__ void __launch_bounds__(128) k_dev(const float* __restrict__ obs,
                                             const double* __restrict__ Yb,
                                             const double2* __restrict__ DC,
                                             const double* __restrict__ part,
                                             float* __restrict__ out) {
    __shared__ double red[2];
    int tid = threadIdx.x;
    int g = tid >> 6;
    double E = 0.0, acc = 0.0;
    float ya[8], yb2[8];
    double Ya[8], Yb2[8];
    double2 ca[8], cb[8];
#pragma unroll
    for (int r = 0; r < 8; ++r) {
        ya[r] = obs[r * OBS + tid];
        Ya[r] = Yb[r * 2 + g];
        ca[r] = DC[r];
    }
    for (int ch = 0; ch < 512; ch += 2) {
        int nb = (ch + 1) * 8;
#pragma unroll
        for (int r = 0; r < 8; ++r) {
            yb2[r] = obs[(nb + r) * OBS + tid];
            Yb2[r] = Yb[(nb + r) * 2 + g];
            cb[r] = DC[nb + r];
        }
#pragma unroll
        for (int r = 0; r < 8; ++r) {
            double e = (double)ya[r] - Ya[r];
            double rho = fma(-ca[r].x, E, e);
            acc = fma(rho * rho, ca[r].y, acc);
            E += e;
        }
        int na = (ch + 2 < 512 ? ch + 2 : 511) * 8;
#pragma unroll
        for (int r = 0; r < 8; ++r) {
            ya[r] = obs[(na + r) * OBS + tid];
            Ya[r] = Yb[(na + r) * 2 + g];
            ca[r] = DC[na + r];
        }
#pragma unroll
        for (int r = 0; r < 8; ++r) {
            double e = (double)yb2[r] - Yb2[r];
            double rho = fma(-cb[r].x, E, e);
            acc = fma(rho * rho, cb[r].y, acc);
            E += e;
        }
    }
#pragma unroll
    for (int off = 32; off; off >>= 1) acc += __shfl_down(acc, off);
    if ((tid & 63) == 0) red[tid >> 6] = acc;
    __syncthreads();
    if (tid == 0) out[0] = (float)(fma(-0.5, red[0] + red[1], part[0]));
}

extern "C" void kernel_launch(void* const* d_in, const int* in_sizes, int n_in,
                              void* d_out, int out_size, void* d_ws, size_t ws_size,
                              hipStream_t stream) {
    const float* obs = (const float*)d_in[0];
    const float* lbs = (const float*)d_in[1];
    const float* lon = (const float*)d_in[2];
    const float* ltn = (const float*)d_in[3];
    float* out = (float*)d_out;
    char* ws = (char*)d_ws;
    double* Yb = (double*)(ws + OFF_YB);
    double2* DC = (double2*)(ws + OFF_DC);
    double* part = (double*)(ws + OFF_PART);

    k_prep<<<T_STEPS / 2, 256, 0, stream>>>(obs, lbs, lon, Yb, DC);
    k_common<<<1, 64, 0, stream>>>(lbs, lon, ltn, Yb, part, out);
    k_dev<<<1, 128, 0, stream>>>(obs, Yb, DC, part, out);
}

// Round 8
// 316.085 us; speedup vs baseline: 6.6380x; 3.4235x over previous
//
#include <hip/hip_runtime.h>

#define T_STEPS 4096
#define OBS 128
#define T0 64                  // serial burn-in; Riccati closed-loop |lambda|~0.15 -> converged ~1e-54
#define TT (T_STEPS - T0)      // 4032 tail steps
#define NCH 63                 // tail chunks
#define CL 64                  // chunk length; NCH*CL == TT
#define D_LOG2PI 1.8378770664093453
#define D_LOG64  4.158883083359672

// ws layout (bytes)
#define OFF_YB   0             // double[4096][2]  : per-group means of y
#define OFF_YBT  65536         // double[2][64][63]: tail means, [g][i][chunk] (coalesced tail reads)
#define OFF_DC   130048        // double2[4096]    : {w_t, inv_delta_t} deviation consts
#define OFF_DEV  195584        // double[2]        : deviation-sector partial sums

// sCB indices
#define CB_M00 0
#define CB_M10 1
#define CB_M11 2
#define CB_K0  3
#define CB_K1  4
#define CB_ML  5   // 5..8 : M^64 row-major
#define CB_M0P 9
#define CB_M0V 10
#define CB_M1P 11
#define CB_M1V 12
#define CB_S   13
#define CB_RCS 14
#define CB_SINF 15
#define CB_V0  16
#define CB_V1  17
#define CB_AR0 18
#define CB_AR1 19
#define CB_A0  20
#define CB_A1  21
#define CB_CC  22
#define CB_AL  23
#define CB_SG0 24
#define CB_SG1 25
#define CB_SGG00 26
#define CB_SGG01 27
#define CB_SGG11 28
#define CB_P00 29
#define CB_P01 30
#define CB_P11 31

// ---------------------------------------------------------------------------
// K0: per-step per-group means (wave shuffle-reduce) written in two layouts
// (time-major for burn/dev, chunk-transposed for tail), + closed-form
// deviation-sector constants.
// ---------------------------------------------------------------------------
__global__ void __launch_bounds__(256) k_prep(const float* __restrict__ obs,
                                              const float* __restrict__ lbs,
                                              const float* __restrict__ lon,
                                              double* __restrict__ Yb,
                                              double* __restrict__ YbT,
                                              double2* __restrict__ DC) {
    int tid = threadIdx.x;
    int wave = tid >> 6, lane = tid & 63;
    int step = blockIdx.x * 2 + (wave >> 1);
    int grp = wave & 1;
    double v = (double)obs[step * OBS + grp * 64 + lane];
#pragma unroll
    for (int off = 32; off; off >>= 1) v += __shfl_down(v, off);
    if (lane == 0) {
        double m = v * (1.0 / 64.0);
        Yb[step * 2 + grp] = m;
        if (step >= T0) {
            int s = step - T0;
            YbT[grp * TT + (s & 63) * NCH + (s >> 6)] = m;
        }
    }
    if (grp == 0 && lane == 1) {
        double beta = exp(2.0 * (double)lbs[0]);
        double s2   = exp(2.0 * (double)lon[0]);
        double den  = fma((double)step, beta, s2);          // s2 + t*beta
        DC[step] = make_double2(beta / den, den / (s2 * (den + beta)));
    }
}

// ---------------------------------------------------------------------------
// K1: deviation sector, closed form (scaled prefix sums). Restructured for
// short serial chains: 8 independent acc chains + off-chain prefix tree so
// the cross-step E chain is 1 f64 add per 8 steps.
// ---------------------------------------------------------------------------
__global__ void __launch_bounds__(128) k_dev(const float* __restrict__ obs,
                                             const double* __restrict__ Yb,
                                             const double2* __restrict__ DC,
                                             double* __restrict__ DEV) {
    int tid = threadIdx.x;
    int g = tid >> 6;
    double E = 0.0;
    double ac0 = 0, ac1 = 0, ac2 = 0, ac3 = 0, ac4 = 0, ac5 = 0, ac6 = 0, ac7 = 0;
    float ya[8]; double Ya[8]; double2 ca[8];
#pragma unroll
    for (int r = 0; r < 8; ++r) {
        ya[r] = obs[r * OBS + tid];
        Ya[r] = Yb[r * 2 + g];
        ca[r] = DC[r];
    }
    for (int ch = 0; ch < 512; ++ch) {
        int nb = (ch + 1 < 512) ? ch + 1 : 511;
        float yn[8]; double Yn[8]; double2 cn[8];
#pragma unroll
        for (int r = 0; r < 8; ++r) {
            yn[r] = obs[(nb * 8 + r) * OBS + tid];
            Yn[r] = Yb[(nb * 8 + r) * 2 + g];
            cn[r] = DC[nb * 8 + r];
        }
        double e0 = (double)ya[0] - Ya[0];
        double e1 = (double)ya[1] - Ya[1];
        double e2 = (double)ya[2] - Ya[2];
        double e3 = (double)ya[3] - Ya[3];
        double e4 = (double)ya[4] - Ya[4];
        double e5 = (double)ya[5] - Ya[5];
        double e6 = (double)ya[6] - Ya[6];
        double e7 = (double)ya[7] - Ya[7];
        double p01 = e0 + e1, p23 = e2 + e3, p45 = e4 + e5, p67 = e6 + e7;
        double p03 = p01 + p23, p47 = p45 + p67;
        double tot = p03 + p47;
        double r0 = fma(-ca[0].x, E, e0);
        double r1 = fma(-ca[1].x, E + e0, e1);
        double r2 = fma(-ca[2].x, E + p01, e2);
        double r3 = fma(-ca[3].x, E + (p01 + e2), e3);
        double r4 = fma(-ca[4].x, E + p03, e4);
        double r5 = fma(-ca[5].x, E + (p03 + e4), e5);
        double r6 = fma(-ca[6].x, E + (p03 + p45), e6);
        double r7 = fma(-ca[7].x, E + ((p03 + p45) + e6), e7);
        ac0 = fma(r0 * r0, ca[0].y, ac0);
        ac1 = fma(r1 * r1, ca[1].y, ac1);
        ac2 = fma(r2 * r2, ca[2].y, ac2);
        ac3 = fma(r3 * r3, ca[3].y, ac3);
        ac4 = fma(r4 * r4, ca[4].y, ac4);
        ac5 = fma(r5 * r5, ca[5].y, ac5);
        ac6 = fma(r6 * r6, ca[6].y, ac6);
        ac7 = fma(r7 * r7, ca[7].y, ac7);
        E += tot;
#pragma unroll
        for (int r = 0; r < 8; ++r) { ya[r] = yn[r]; Ya[r] = Yn[r]; ca[r] = cn[r]; }
    }
    double acc = ((ac0 + ac1) + (ac2 + ac3)) + ((ac4 + ac5) + (ac6 + ac7));
#pragma unroll
    for (int off = 32; off; off >>= 1) acc += __shfl_down(acc, off);
    if ((tid & 63) == 0) DEV[g] = acc;
}

// ---------------------------------------------------------------------------
// K2: merged common sector — phase 1 (lane 0): exact bias-free 2x2 burn-in
// (Friedland decomposition) + converged constants + g-table into LDS;
// phase 2 (126 lanes): parallel tail chunks; phase 3 (lane 0): stitch,
// closed-form bias marginalization, all outputs.
// ---------------------------------------------------------------------------
__global__ void __launch_bounds__(128) k_common2(const float* __restrict__ lbs,
                                                 const float* __restrict__ lon,
                                                 const float* __restrict__ ltn,
                                                 const double* __restrict__ Yb,
                                                 const double* __restrict__ YbT,
                                                 const double* __restrict__ DEV,
                                                 float* __restrict__ out) {
    __shared__ double sCB[32];
    __shared__ double2 sG[CL];
    __shared__ double sCH[2 * NCH * 6];
    int tid = threadIdx.x;

    if (tid == 0) {
        const double s2 = exp(2.0 * (double)lon[0]);
        const double q2 = exp(2.0 * (double)ltn[0]);
        const double q23 = q2 * (1.0 / 3.0), q22 = 0.5 * q2, rbar = s2 * (1.0 / 64.0);
        double P00 = 100.0, P01 = 0.0, P11 = 100.0;
        double V0 = 0.0, V1 = 0.0;
        double m0p = 0, m0v = 0, m1p = 0, m1v = 0;
        double aR0 = 0, aR1 = 0, a0 = 0, a1 = 0, cc = 0, aL = 0;
        double S = 1.0, rc = 1.0, K0 = 0.0, K1 = 0.0;
        const double2* Yp = (const double2*)Yb;
        double2 cur[8];
#pragma unroll
        for (int r = 0; r < 8; ++r) cur[r] = Yp[r];
        for (int ch = 0; ch < T0 / 8; ++ch) {
            int nc = (ch + 1 < T0 / 8) ? ch + 1 : T0 / 8 - 1;
            double2 nxt[8];
#pragma unroll
            for (int r = 0; r < 8; ++r) nxt[r] = Yp[nc * 8 + r];
#pragma unroll
            for (int r = 0; r < 8; ++r) {
                double2 Y = cur[r];
                double X00 = fma(2.0, P01, P00) + P11 + q23;
                double X01 = P01 + P11 + q22;
                double X11 = P11 + q2;
                S = X00 + rbar;
                rc = (double)(1.0f / (float)S);
                rc = fma(fma(-S, rc, 1.0), rc, rc);
                rc = fma(fma(-S, rc, 1.0), rc, rc);
                K0 = X00 * rc; K1 = X01 * rc;
                P00 = fma(-K0, X00, X00);
                P01 = fma(-K0, X01, X01);
                P11 = fma(-K1, X01, X11);
                double Vp0 = V0 + V1;
                double s = 1.0 + Vp0;
                V0 = fma(-K0, s, Vp0);
                V1 = fma(-K1, s, V1);
                double mp0 = m0p + m0v, mp1 = m1p + m1v;
                double rr0 = Y.x - mp0, rr1 = Y.y - mp1;
                m0p = fma(K0, rr0, mp0); m0v = fma(K1, rr0, m0v);
                m1p = fma(K0, rr1, mp1); m1v = fma(K1, rr1, m1v);
                double src = s * rc;
                aR0 = fma(rc * rr0, rr0, aR0);
                aR1 = fma(rc * rr1, rr1, aR1);
                a0 = fma(src, rr0, a0);
                a1 = fma(src, rr1, a1);
                cc = fma(src, s, cc);
                aL += (double)__logf((float)S);
            }
#pragma unroll
            for (int r = 0; r < 8; ++r) cur[r] = nxt[r];
        }
        // closed-loop M = A - K e'A : M00=M01=1-K0, M10=-K1, M11=1-K1
        double M00 = 1.0 - K0, M10 = -K1, M11 = 1.0 - K1;
        double gv0 = 1.0, gv1 = 1.0;     // g_0 = e'A = (1,1)
        double Sg0 = 0, Sg1 = 0, Sgg00 = 0, Sgg01 = 0, Sgg11 = 0;
        for (int i = 0; i < CL; ++i) {
            sG[i] = make_double2(gv0, gv1);
            Sg0 += gv0; Sg1 += gv1;
            Sgg00 = fma(gv0, gv0, Sgg00);
            Sgg01 = fma(gv0, gv1, Sgg01);
            Sgg11 = fma(gv1, gv1, Sgg11);
            double n0 = fma(gv0, M00, gv1 * M10);
            double n1 = fma(gv0, M00, gv1 * M11);   // M01 == M00
            gv0 = n0; gv1 = n1;
        }
        double A_ = M00, B_ = M00, C_ = M10, D_ = M11;   // M^64 via 6 squarings
        for (int i = 0; i < 6; ++i) {
            double na = fma(A_, A_, B_ * C_);
            double nb2 = fma(A_, B_, B_ * D_);
            double nc2 = fma(C_, A_, D_ * C_);
            double nd = fma(C_, B_, D_ * D_);
            A_ = na; B_ = nb2; C_ = nc2; D_ = nd;
        }
        sCB[CB_M00] = M00; sCB[CB_M10] = M10; sCB[CB_M11] = M11;
        sCB[CB_K0] = K0; sCB[CB_K1] = K1;
        sCB[CB_ML + 0] = A_; sCB[CB_ML + 1] = B_; sCB[CB_ML + 2] = C_; sCB[CB_ML + 3] = D_;
        sCB[CB_M0P] = m0p; sCB[CB_M0V] = m0v; sCB[CB_M1P] = m1p; sCB[CB_M1V] = m1v;
        sCB[CB_S] = S; sCB[CB_RCS] = rc; sCB[CB_SINF] = 1.0 + V0 + V1;
        sCB[CB_V0] = V0; sCB[CB_V1] = V1;
        sCB[CB_AR0] = aR0; sCB[CB_AR1] = aR1; sCB[CB_A0] = a0; sCB[CB_A1] = a1;
        sCB[CB_CC] = cc; sCB[CB_AL] = aL;
        sCB[CB_SG0] = Sg0; sCB[CB_SG1] = Sg1;
        sCB[CB_SGG00] = Sgg00; sCB[CB_SGG01] = Sgg01; sCB[CB_SGG11] = Sgg11;
        sCB[CB_P00] = P00; sCB[CB_P01] = P01; sCB[CB_P11] = P11;
    }
    __syncthreads();

    if (tid < 2 * NCH) {
        int g = (tid >= NCH) ? 1 : 0;
        int c = tid - g * NCH;
        double M00 = sCB[CB_M00], M10 = sCB[CB_M10], M11 = sCB[CB_M11];
        double K0 = sCB[CB_K0], K1 = sCB[CB_K1];
        const double* yt = YbT + g * TT + c;      // stride NCH between i's
        double u0 = 0, u1 = 0, Sw = 0, Sw2 = 0, Sgw0 = 0, Sgw1 = 0;
        double yc[8];
#pragma unroll
        for (int r = 0; r < 8; ++r) yc[r] = yt[r * NCH];
        for (int b = 0; b < 8; ++b) {
            int nb = (b + 1 < 8) ? b + 1 : 7;
            double yn[8];
#pragma unroll
            for (int r = 0; r < 8; ++r) yn[r] = yt[(nb * 8 + r) * NCH];
#pragma unroll
            for (int r = 0; r < 8; ++r) {
                double y = yc[r];
                double2 gi = sG[b * 8 + r];
                double w = y - u0 - u1;            // w_i = y_i - e'A u_i
                Sw += w; Sw2 = fma(w, w, Sw2);
                Sgw0 = fma(gi.x, w, Sgw0);
                Sgw1 = fma(gi.y, w, Sgw1);
                double nu0 = fma(M00, u0 + u1, K0 * y);   // M01 == M00
                double nu1 = fma(M10, u0, fma(M11, u1, K1 * y));
                u0 = nu0; u1 = nu1;
            }
#pragma unroll
            for (int r = 0; r < 8; ++r) yc[r] = yn[r];
        }
        double* o = sCH + tid * 6;
        o[0] = u0; o[1] = u1; o[2] = Sw; o[3] = Sw2; o[4] = Sgw0; o[5] = Sgw1;
    }
    __syncthreads();

    if (tid == 0) {
        double ML00 = sCB[CB_ML], ML01 = sCB[CB_ML + 1], ML10 = sCB[CB_ML + 2], ML11 = sCB[CB_ML + 3];
        double Sg0 = sCB[CB_SG0], Sg1 = sCB[CB_SG1];
        double Sgg00 = sCB[CB_SGG00], Sgg01 = sCB[CB_SGG01], Sgg11 = sCB[CB_SGG11];
        double m0p = sCB[CB_M0P], m0v = sCB[CB_M0V], m1p = sCB[CB_M1P], m1v = sCB[CB_M1V];
        double SR0 = 0, SR1 = 0, SR20 = 0, SR21 = 0;
        for (int c = 0; c < NCH; ++c) {
            const double* Ap = sCH + c * 6;
            const double* Bp = sCH + (NCH + c) * 6;
            double q0 = Sgg00 * m0p * m0p + 2.0 * Sgg01 * m0p * m0v + Sgg11 * m0v * m0v;
            SR0 += Ap[2] - (Sg0 * m0p + Sg1 * m0v);
            SR20 += Ap[3] - 2.0 * (Ap[4] * m0p + Ap[5] * m0v) + q0;
            double n0p = fma(ML00, m0p, fma(ML01, m0v, Ap[0]));
            double n0v = fma(ML10, m0p, fma(ML11, m0v, Ap[1]));
            m0p = n0p; m0v = n0v;
            double q1 = Sgg00 * m1p * m1p + 2.0 * Sgg01 * m1p * m1v + Sgg11 * m1v * m1v;
            SR1 += Bp[2] - (Sg0 * m1p + Sg1 * m1v);
            SR21 += Bp[3] - 2.0 * (Bp[4] * m1p + Bp[5] * m1v) + q1;
            double n1p = fma(ML00, m1p, fma(ML01, m1v, Bp[0]));
            double n1v = fma(ML10, m1p, fma(ML11, m1v, Bp[1]));
            m1p = n1p; m1v = n1v;
        }
        double beta = exp(2.0 * (double)lbs[0]);
        double s2 = exp(2.0 * (double)lon[0]);
        double Sst = sCB[CB_S], rcS = sCB[CB_RCS], sI = sCB[CB_SINF];
        double V0 = sCB[CB_V0], V1 = sCB[CB_V1];
        double aR0 = sCB[CB_AR0] + SR20 * rcS, aR1 = sCB[CB_AR1] + SR21 * rcS;
        double a0 = sCB[CB_A0] + sI * rcS * SR0, a1 = sCB[CB_A1] + sI * rcS * SR1;
        double ccT = sCB[CB_CC] + (double)TT * sI * sI * rcS;
        double aL = sCB[CB_AL] + (double)TT * log(Sst);
        double pi0 = 64.0 / beta;
        double piT = pi0 + ccT;
        double b0 = a0 / piT, b1 = a1 / piT, sB = 1.0 / piT;
        double logpc = -0.5 * (aR0 + aR1) + 0.5 * (a0 * a0 + a1 * a1) / piT
                     - aL - log(piT / pi0);
        double sld = (double)(T_STEPS - 1) * log(s2) + log(fma((double)T_STEPS, beta, s2));
        double part = logpc - 63.0 * sld - (double)T_STEPS * (D_LOG64 + 64.0 * D_LOG2PI);
        double dev = DEV[0] + DEV[1];
        out[0] = (float)(part - 0.5 * dev);
        out[1] = (float)(m0p + V0 * b0); out[2] = (float)(m1p + V0 * b1);
        out[3] = (float)(m0v + V1 * b0); out[4] = (float)(m1v + V1 * b1);
        double Paa = sCB[CB_P00] + sB * V0 * V0;
        double Pac = sCB[CB_P01] + sB * V0 * V1;
        double Pcc = sCB[CB_P11] + sB * V1 * V1;
        out[5]  = (float)Paa; out[6]  = 0.0f;       out[7]  = (float)Pac; out[8]  = 0.0f;
        out[9]  = 0.0f;       out[10] = (float)Paa; out[11] = 0.0f;       out[12] = (float)Pac;
        out[13] = (float)Pac; out[14] = 0.0f;       out[15] = (float)Pcc; out[16] = 0.0f;
        out[17] = 0.0f;       out[18] = (float)Pac; out[19] = 0.0f;       out[20] = (float)Pcc;
    }
}

extern "C" void kernel_launch(void* const* d_in, const int* in_sizes, int n_in,
                              void* d_out, int out_size, void* d_ws, size_t ws_size,
                              hipStream_t stream) {
    const float* obs = (const float*)d_in[0];
    const float* lbs = (const float*)d_in[1];
    const float* lon = (const float*)d_in[2];
    const float* ltn = (const float*)d_in[3];
    float* out = (float*)d_out;
    char* ws = (char*)d_ws;
    double* Yb = (double*)(ws + OFF_YB);
    double* YbT = (double*)(ws + OFF_YBT);
    double2* DC = (double2*)(ws + OFF_DC);
    double* DEVp = (double*)(ws + OFF_DEV);

    k_prep<<<T_STEPS / 2, 256, 0, stream>>>(obs, lbs, lon, Yb, YbT, DC);
    k_dev<<<1, 128, 0, stream>>>(obs, Yb, DC, DEVp);
    k_common2<<<1, 128, 0, stream>>>(lbs, lon, ltn, Yb, YbT, DEVp, out);
}